// Round 3
// baseline (485.195 us; speedup 1.0000x reference)
//
#include <hip/hip_runtime.h>

#define NIN 64
#define NOUT 32
#define TBITS 21                 // 128^3 stride-2 lattice
#define TSIZE (1 << TBITS)
#define NB 512                   // buckets: 64 spatial cells (64^3) x 8 parity classes
#define NT 4                     // tiles per wave in gen_conv (software pipeline depth)

typedef __attribute__((ext_vector_type(8))) short short8;
typedef __attribute__((ext_vector_type(4))) float float4v;
typedef __attribute__((ext_vector_type(4))) unsigned short ushort4v;

__device__ __forceinline__ unsigned short bf16rne(float x) {
    unsigned u = __float_as_uint(x);
    u += 0x7fffu + ((u >> 16) & 1u);
    return (unsigned short)(u >> 16);
}

__device__ __forceinline__ int bucket_of(int4 q, int* cls) {
    int c = (q.y & 1) | ((q.z & 1) << 1) | ((q.w & 1) << 2);
    *cls = c;
    // spatial-major (64^3 cells): all 8 classes of one cell adjacent in bucket order
    int sp = (((q.w & 255) >> 6) << 4) | (((q.z & 255) >> 6) << 2) | ((q.y & 255) >> 6);
    return (sp << 3) | c;
}

// ws (ints): [0,TSIZE) table | [TSIZE, TSIZE+2*SC) sorted int2 (-1 padded) |
//   A=TSIZE+2*SC: count[NB] | cursor[NB] at A+NB | total[4] at A+2NB |
//   wt bf16 [27][32][64] at A+2NB+4 | fb bf16 [Np][64] after wt
__global__ void prep(int4* __restrict__ ws4, int n4,
                     int4* __restrict__ count4,
                     const float* __restrict__ w, unsigned short* __restrict__ wt,
                     const float* __restrict__ f, unsigned short* __restrict__ fb,
                     int fn4) {
    int i = blockIdx.x * blockDim.x + threadIdx.x;
    if (i < n4) ws4[i] = make_int4(-1, -1, -1, -1);
    if (i < NB / 4) count4[i] = make_int4(0, 0, 0, 0);
    if (i < 27 * 64 * 32) {          // fp32 [27][64][32] -> bf16 [27][32][64]
        int oi = i >> 11;
        int k  = (i >> 5) & 63;
        int ch = i & 31;
        wt[oi * 2048 + ch * 64 + k] = bf16rne(w[i]);
    }
    if (i < fn4) {                   // fp32 feats -> bf16 mirror, 4/thread
        float4 v = ((const float4*)f)[i];
        ushort4v o;
        o.x = bf16rne(v.x); o.y = bf16rne(v.y);
        o.z = bf16rne(v.z); o.w = bf16rne(v.w);
        ((ushort4v*)fb)[i] = o;
    }
}

// build hash table (needs table init) + count bucket sizes (independent)
__global__ void bc(const int* __restrict__ coords, int np, int* __restrict__ table,
                   const int* __restrict__ guide, int ng, int* __restrict__ count) {
    int i = blockIdx.x * blockDim.x + threadIdx.x;
    if (i < np) {
        int x = coords[i * 4 + 1];
        int y = coords[i * 4 + 2];
        int z = coords[i * 4 + 3];
        table[(x >> 1) | ((y >> 1) << 7) | ((z >> 1) << 14)] = i;
    }
    if (i < ng) {
        int c;
        int b = bucket_of(((const int4*)guide)[i], &c);
        atomicAdd(&count[b], 1);
    }
}

// exclusive scan of 16-padded bucket sizes; one block of 128, 4 buckets/thread
__global__ void scanB(const int* __restrict__ count, int* __restrict__ cursor,
                      int* __restrict__ total) {
    __shared__ int ps[128];
    int t = threadIdx.x;
    int4 c4 = ((const int4*)count)[t];
    int p0 = (c4.x + 15) & ~15, p1 = (c4.y + 15) & ~15;
    int p2 = (c4.z + 15) & ~15, p3 = (c4.w + 15) & ~15;
    ps[t] = p0 + p1 + p2 + p3;
    __syncthreads();
    for (int off = 1; off < 128; off <<= 1) {
        int v = ps[t];
        int u = (t >= off) ? ps[t - off] : 0;
        __syncthreads();
        ps[t] = v + u;
        __syncthreads();
    }
    int excl = (t == 0) ? 0 : ps[t - 1];
    int4 o;
    o.x = excl; o.y = excl + p0; o.z = excl + p0 + p1; o.w = excl + p0 + p1 + p2;
    ((int4*)cursor)[t] = o;
    if (t == 127) total[0] = ps[127];
}

// scatter guides to bucketed slots; entry = {id | class<<24, x+1 | y+1<<9 | z+1<<18}
__global__ void scat(const int* __restrict__ guide, int ng,
                     int* __restrict__ cursor, int2* __restrict__ sorted) {
    int i = blockIdx.x * blockDim.x + threadIdx.x;
    if (i >= ng) return;
    int4 q = ((const int4*)guide)[i];
    int c;
    int b = bucket_of(q, &c);
    int pos = atomicAdd(&cursor[b], 1);
    int2 e;
    e.x = i | (c << 24);
    e.y = (q.y + 1) | ((q.z + 1) << 9) | ((q.w + 1) << 18);
    sorted[pos] = e;
}

// probe both rounds for one tile entry; inadmissible/miss -> -1
__device__ __forceinline__ void probe2(const int* __restrict__ table, int2 s2,
                                       int quad, int* o0, int* o1, int* oc) {
    int c = (__builtin_amdgcn_readfirstlane(s2.x) >> 24) & 7;
    int qx = (s2.y & 511) - 1;
    int qy = ((s2.y >> 9) & 511) - 1;
    int qz = ((s2.y >> 18) & 511) - 1;
    int res[2];
    #pragma unroll
    for (int r = 0; r < 2; ++r) {
        int sub = quad + r * 4;
        int offx = (c & 1) ? ((sub & 1) ? 1 : -1) : 0;
        int offy = (c & 2) ? ((sub & 2) ? 1 : -1) : 0;
        int offz = (c & 4) ? ((sub & 4) ? 1 : -1) : 0;
        int px = qx - offx, py = qy - offy, pz = qz - offz;
        bool valid = (s2.x >= 0) & ((sub & ~c & 7) == 0) &
                     ((unsigned)px < 256u) & ((unsigned)py < 256u) & ((unsigned)pz < 256u);
        int lin = (px >> 1) | ((py >> 1) << 7) | ((pz >> 1) << 14);
        int v = table[valid ? lin : 0];
        res[r] = valid ? v : -1;
    }
    *o0 = res[0]; *o1 = res[1]; *oc = c;
}

template<int USEFB>
__device__ __forceinline__ void loadA(const float* __restrict__ feats,
                                      const unsigned short* __restrict__ fb,
                                      int hidx, int quad, short8* a0, short8* a1) {
    short8 z = {0,0,0,0,0,0,0,0};
    *a0 = z; *a1 = z;
    if (hidx >= 0) {
        if constexpr (USEFB) {
            const unsigned short* fp = fb + (size_t)hidx * NIN + quad * 8;
            *a0 = *(const short8*)fp;
            *a1 = *(const short8*)(fp + 32);
        } else {
            const float4* fp = (const float4*)(feats + (size_t)hidx * NIN + quad * 8);
            float4 fA = fp[0], fB = fp[1];
            const float4* fp2 = (const float4*)(feats + (size_t)hidx * NIN + 32 + quad * 8);
            float4 fC = fp2[0], fD = fp2[1];
            short8 x, y;
            x[0] = (short)bf16rne(fA.x); x[1] = (short)bf16rne(fA.y);
            x[2] = (short)bf16rne(fA.z); x[3] = (short)bf16rne(fA.w);
            x[4] = (short)bf16rne(fB.x); x[5] = (short)bf16rne(fB.y);
            x[6] = (short)bf16rne(fB.z); x[7] = (short)bf16rne(fB.w);
            y[0] = (short)bf16rne(fC.x); y[1] = (short)bf16rne(fC.y);
            y[2] = (short)bf16rne(fC.z); y[3] = (short)bf16rne(fC.w);
            y[4] = (short)bf16rne(fD.x); y[5] = (short)bf16rne(fD.y);
            y[6] = (short)bf16rne(fD.z); y[7] = (short)bf16rne(fD.w);
            *a0 = x; *a1 = y;
        }
    }
}

__device__ __forceinline__ void slotMM(const unsigned short* __restrict__ wt,
                                       int c, int sub, int m, int quad,
                                       short8 a0, short8 a1,
                                       float4v* acc0, float4v* acc1) {
    int offx = (c & 1) ? ((sub & 1) ? 1 : -1) : 0;
    int offy = (c & 2) ? ((sub & 2) ? 1 : -1) : 0;
    int offz = (c & 4) ? ((sub & 4) ? 1 : -1) : 0;
    int oi = (offx + 1) * 9 + (offy + 1) * 3 + (offz + 1);
    const unsigned short* wb = wt + oi * 2048 + m * 64 + quad * 8;
    short8 b00 = *(const short8*)(wb);               // k<32,  ch m
    short8 b01 = *(const short8*)(wb + 1024);        // k<32,  ch 16+m
    short8 b10 = *(const short8*)(wb + 32);          // k>=32, ch m
    short8 b11 = *(const short8*)(wb + 1024 + 32);   // k>=32, ch 16+m
    *acc0 = __builtin_amdgcn_mfma_f32_16x16x32_bf16(a0, b00, *acc0, 0, 0, 0);
    *acc0 = __builtin_amdgcn_mfma_f32_16x16x32_bf16(a1, b10, *acc0, 0, 0, 0);
    *acc1 = __builtin_amdgcn_mfma_f32_16x16x32_bf16(a0, b01, *acc1, 0, 0, 0);
    *acc1 = __builtin_amdgcn_mfma_f32_16x16x32_bf16(a1, b11, *acc1, 0, 0, 0);
}

// ---- main: each wave owns NT consecutive 16-row tiles (uniform class per tile,
// spatially bucketed). Per-tile chain {sorted -> probe -> shfl -> gather -> MFMA ->
// store} is software-pipelined: tile t+1's sorted load issues at iteration top,
// its probes issue after tile t's GEMM loads (kept in flight across the loop via
// in-order vmcnt), so the chain latency hides under tile t's compute. ----
template<int USEFB>
__launch_bounds__(256, 4)
__global__ void gen_conv(const float* __restrict__ feats,        // [Np,64] fp32
                         const unsigned short* __restrict__ fb,  // [Np,64] bf16
                         const float* __restrict__ bias,         // [32]
                         const int* __restrict__ table,          // [2^21]
                         const int2* __restrict__ sorted,        // padded, w/ coords
                         const int* __restrict__ totalp,         // [1]
                         const unsigned short* __restrict__ wt,  // [27][32][64] bf16
                         float* __restrict__ out) {
    // bijective XCD swizzle: consecutive tiles stay on one XCD's L2
    int nwg = gridDim.x;
    int orig = blockIdx.x;
    int qd = nwg >> 3, rd = nwg & 7;
    int xc = orig & 7, ix = orig >> 3;
    int wg = (xc < rd ? xc * (qd + 1) : rd * (qd + 1) + (xc - rd) * qd) + ix;

    int wave = wg * 4 + (threadIdx.x >> 6);
    int lane = threadIdx.x & 63;
    int m    = lane & 15;          // guide-row in tile / B n-col
    int quad = lane >> 4;          // k-octet / probe slot base

    int ntile = totalp[0] >> 4;    // total is 16-aligned
    int t0 = wave * NT;
    if (t0 >= ntile) return;
    int tend = t0 + NT; if (tend > ntile) tend = ntile;

    float bv0 = bias[m], bv1 = bias[16 + m];

    // prologue: stage tile t0
    int2 s2 = sorted[t0 * 16 + m];
    int idx0, idx1, cc;
    probe2(table, s2, quad, &idx0, &idx1, &cc);

    for (int t = t0; t < tend; ++t) {
        bool more = (t + 1 < tend);
        int2 s2n = s2;
        if (more) s2n = sorted[(t + 1) * 16 + m];   // issue early

        int c = cc;
        int id = (s2.x < 0) ? -1 : (s2.x & 0xffffff);

        // per-slot gathered row indices (slot s covers rows via lane group s&3)
        int h0 = __shfl(idx0, m, 64);
        int h1 = __shfl(idx0, 16 + m, 64);
        int h2 = __shfl(idx0, 32 + m, 64);
        int h3 = __shfl(idx0, 48 + m, 64);
        int h4 = __shfl(idx1, m, 64);
        int h5 = __shfl(idx1, 16 + m, 64);
        int h6 = __shfl(idx1, 32 + m, 64);
        int h7 = __shfl(idx1, 48 + m, 64);

        float4v acc0 = {0.f, 0.f, 0.f, 0.f};
        float4v acc1 = {0.f, 0.f, 0.f, 0.f};

        // half 1: slots 0..3 — batch A gathers, then B+MFMA
        short8 a00, a01, a10, a11, a20, a21, a30, a31;
        loadA<USEFB>(feats, fb, h0, quad, &a00, &a01);
        loadA<USEFB>(feats, fb, h1, quad, &a10, &a11);
        loadA<USEFB>(feats, fb, h2, quad, &a20, &a21);
        loadA<USEFB>(feats, fb, h3, quad, &a30, &a31);
        slotMM(wt, c, 0, m, quad, a00, a01, &acc0, &acc1);
        slotMM(wt, c, 1, m, quad, a10, a11, &acc0, &acc1);
        slotMM(wt, c, 2, m, quad, a20, a21, &acc0, &acc1);
        slotMM(wt, c, 3, m, quad, a30, a31, &acc0, &acc1);

        // half 2: slots 4..7
        short8 a40, a41, a50, a51, a60, a61, a70, a71;
        loadA<USEFB>(feats, fb, h4, quad, &a40, &a41);
        loadA<USEFB>(feats, fb, h5, quad, &a50, &a51);
        loadA<USEFB>(feats, fb, h6, quad, &a60, &a61);
        loadA<USEFB>(feats, fb, h7, quad, &a70, &a71);
        slotMM(wt, c, 4, m, quad, a40, a41, &acc0, &acc1);
        slotMM(wt, c, 5, m, quad, a50, a51, &acc0, &acc1);
        slotMM(wt, c, 6, m, quad, a60, a61, &acc0, &acc1);
        slotMM(wt, c, 7, m, quad, a70, a71, &acc0, &acc1);

        // next-tile probes: issued as the LAST loads of the iteration so MFMA
        // waits (through their own B loads) leave these in flight
        int nidx0 = idx0, nidx1 = idx1, ncc = cc;
        if (more) probe2(table, s2n, quad, &nidx0, &nidx1, &ncc);

        // existence + stores: lane's col n=m; rows mr=quad*4+r
        unsigned long long eb = __ballot(idx0 >= 0) | __ballot(idx1 >= 0);
        unsigned e16 = (unsigned)((eb | (eb >> 16) | (eb >> 32) | (eb >> 48)) & 0xffffull);
        #pragma unroll
        for (int r = 0; r < 4; ++r) {
            int mr = quad * 4 + r;
            int idr = __shfl(id, mr, 64);
            if (idr >= 0) {
                bool exr = (e16 >> mr) & 1;
                out[(size_t)idr * NOUT + m]      = exr ? (acc0[r] + bv0) : 0.f;
                out[(size_t)idr * NOUT + 16 + m] = exr ? (acc1[r] + bv1) : 0.f;
            }
        }

        s2 = s2n; idx0 = nidx0; idx1 = nidx1; cc = ncc;
    }
}

extern "C" void kernel_launch(void* const* d_in, const int* in_sizes, int n_in,
                              void* d_out, int out_size, void* d_ws, size_t ws_size,
                              hipStream_t stream) {
    const float* feats   = (const float*)d_in[0];
    const float* weights = (const float*)d_in[1];
    const float* bias    = (const float*)d_in[2];
    const int*   coords  = (const int*)d_in[3];
    const int*   guide   = (const int*)d_in[4];
    float* out = (float*)d_out;

    int np = in_sizes[3] / 4;
    int ng = in_sizes[4] / 4;

    int* wsI = (int*)d_ws;
    int SC = (ng + NB * 16 + 3) & ~3;        // bucketed capacity (entries)
    int A = TSIZE + 2 * SC;                  // sorted is int2
    int* table   = wsI;                      // 2^21
    int2* sorted = (int2*)(wsI + TSIZE);     // SC entries, -1 padded
    int* count   = wsI + A;                  // NB
    int* cursor  = wsI + A + NB;             // NB
    int* total   = wsI + A + 2 * NB;         // 1 (+3 pad)
    unsigned short* wt = (unsigned short*)(wsI + A + 2 * NB + 4);   // 27*32*64 bf16
    unsigned short* fb = (unsigned short*)(wsI + A + 2 * NB + 4 + 27648);
    size_t need = ((size_t)A + 2 * NB + 4 + 27648) * 4 + (size_t)np * NIN * 2;
    int usefb = (ws_size >= need) ? 1 : 0;

    int n4 = A / 4;
    int fn4 = usefb ? np * (NIN / 4) : 0;
    int prep_n = n4 > fn4 ? n4 : fn4;
    if (prep_n < 27 * 64 * 32) prep_n = 27 * 64 * 32;
    hipLaunchKernelGGL(prep, dim3((prep_n + 255) / 256), dim3(256), 0, stream,
                       (int4*)wsI, n4, (int4*)count, weights, wt, feats, fb, fn4);

    int bc_n = np > ng ? np : ng;
    hipLaunchKernelGGL(bc, dim3((bc_n + 255) / 256), dim3(256), 0, stream,
                       coords, np, table, guide, ng, count);

    hipLaunchKernelGGL(scanB, dim3(1), dim3(128), 0, stream, count, cursor, total);

    hipLaunchKernelGGL(scat, dim3((ng + 255) / 256), dim3(256), 0, stream,
                       guide, ng, cursor, sorted);

    int maxtiles = (ng + NB * 15 + 15) / 16;
    int blocks = (maxtiles + NT * 4 - 1) / (NT * 4);   // 4 waves/block, NT tiles/wave
    if (usefb) {
        hipLaunchKernelGGL((gen_conv<1>), dim3(blocks), dim3(256), 0, stream,
                           feats, fb, bias, table, sorted, total, wt, out);
    } else {
        hipLaunchKernelGGL((gen_conv<0>), dim3(blocks), dim3(256), 0, stream,
                           feats, fb, bias, table, sorted, total, wt, out);
    }
}

// Round 5
// 251.673 us; speedup vs baseline: 1.9279x; 1.9279x over previous
//
#include <hip/hip_runtime.h>

#define NIN 64
#define NOUT 32
#define TBITS 21                 // 128^3 stride-2 lattice
#define TSIZE (1 << TBITS)
#define NB 512                   // buckets: 64 spatial cells (64^3) x 8 parity classes
#define NT 4                     // tiles per wave in gen_conv (software pipeline depth)
#define CHUNK 4096               // guides per block in bc/scat (LDS histogram chunk)
#define KPT (CHUNK / 256)        // elements per thread in scat

typedef __attribute__((ext_vector_type(8))) short short8;
typedef __attribute__((ext_vector_type(4))) float float4v;
typedef __attribute__((ext_vector_type(4))) unsigned short ushort4v;

__device__ __forceinline__ unsigned short bf16rne(float x) {
    unsigned u = __float_as_uint(x);
    u += 0x7fffu + ((u >> 16) & 1u);
    return (unsigned short)(u >> 16);
}

__device__ __forceinline__ int bucket_of(int4 q, int* cls) {
    int c = (q.y & 1) | ((q.z & 1) << 1) | ((q.w & 1) << 2);
    *cls = c;
    // spatial-major (64^3 cells): all 8 classes of one cell adjacent in bucket order
    int sp = (((q.w & 255) >> 6) << 4) | (((q.z & 255) >> 6) << 2) | ((q.y & 255) >> 6);
    return (sp << 3) | c;
}

// ws (ints): [0,TSIZE) table | [TSIZE, TSIZE+2*SC) sorted int2 (-1 padded) |
//   A=TSIZE+2*SC: count[NB] | cursor[NB] at A+NB | total[4] at A+2NB |
//   wt bf16 [27][32][64] at A+2NB+4 | fb bf16 [Np][64] after wt
__global__ void prep(int4* __restrict__ ws4, int n4,
                     int4* __restrict__ count4,
                     const float* __restrict__ w, unsigned short* __restrict__ wt,
                     const float* __restrict__ f, unsigned short* __restrict__ fb,
                     int fn4) {
    int i = blockIdx.x * blockDim.x + threadIdx.x;
    if (i < n4) ws4[i] = make_int4(-1, -1, -1, -1);
    if (i < NB / 4) count4[i] = make_int4(0, 0, 0, 0);
    if (i < 27 * 64 * 32) {          // fp32 [27][64][32] -> bf16 [27][32][64]
        int oi = i >> 11;
        int k  = (i >> 5) & 63;
        int ch = i & 31;
        wt[oi * 2048 + ch * 64 + k] = bf16rne(w[i]);
    }
    if (i < fn4) {                   // fp32 feats -> bf16 mirror, 4/thread
        float4 v = ((const float4*)f)[i];
        ushort4v o;
        o.x = bf16rne(v.x); o.y = bf16rne(v.y);
        o.z = bf16rne(v.z); o.w = bf16rne(v.w);
        ((ushort4v*)fb)[i] = o;
    }
}

// build hash table (1 store/thread) + chunked LDS-histogram bucket count:
// one global atomic per (block, non-empty bucket) instead of per guide.
__global__ void bc(const int* __restrict__ coords, int np, int* __restrict__ table,
                   const int* __restrict__ guide, int ng, int* __restrict__ count) {
    __shared__ int hist[NB];
    for (int i = threadIdx.x; i < NB; i += blockDim.x) hist[i] = 0;
    int gi = blockIdx.x * blockDim.x + threadIdx.x;
    if (gi < np) {
        int x = coords[gi * 4 + 1];
        int y = coords[gi * 4 + 2];
        int z = coords[gi * 4 + 3];
        table[(x >> 1) | ((y >> 1) << 7) | ((z >> 1) << 14)] = gi;
    }
    __syncthreads();
    int base = blockIdx.x * CHUNK;
    if (base < ng) {
        int end = base + CHUNK; if (end > ng) end = ng;
        for (int i = base + threadIdx.x; i < end; i += blockDim.x) {
            int c;
            int b = bucket_of(((const int4*)guide)[i], &c);
            atomicAdd(&hist[b], 1);
        }
        __syncthreads();
        for (int i = threadIdx.x; i < NB; i += blockDim.x)
            if (hist[i]) atomicAdd(&count[i], hist[i]);
    }
}

// exclusive scan of 16-padded bucket sizes; one block of 128, 4 buckets/thread
__global__ void scanB(const int* __restrict__ count, int* __restrict__ cursor,
                      int* __restrict__ total) {
    __shared__ int ps[128];
    int t = threadIdx.x;
    int4 c4 = ((const int4*)count)[t];
    int p0 = (c4.x + 15) & ~15, p1 = (c4.y + 15) & ~15;
    int p2 = (c4.z + 15) & ~15, p3 = (c4.w + 15) & ~15;
    ps[t] = p0 + p1 + p2 + p3;
    __syncthreads();
    for (int off = 1; off < 128; off <<= 1) {
        int v = ps[t];
        int u = (t >= off) ? ps[t - off] : 0;
        __syncthreads();
        ps[t] = v + u;
        __syncthreads();
    }
    int excl = (t == 0) ? 0 : ps[t - 1];
    int4 o;
    o.x = excl; o.y = excl + p0; o.z = excl + p0 + p1; o.w = excl + p0 + p1 + p2;
    ((int4*)cursor)[t] = o;
    if (t == 127) total[0] = ps[127];
}

// chunked scatter: LDS histogram pass for local ranks (registers, static-indexed),
// one global atomic per (block, bucket) for bases, then scatter-write.
// entry = {id | class<<24, x+1 | y+1<<9 | z+1<<18}
__global__ void scat(const int* __restrict__ guide, int ng,
                     int* __restrict__ cursor, int2* __restrict__ sorted) {
    __shared__ int hist[NB];
    int t = threadIdx.x;
    for (int i = t; i < NB; i += 256) hist[i] = 0;
    __syncthreads();
    int base = blockIdx.x * CHUNK;
    int packed[KPT];                 // (bucket<<13) | lrank, or -1
    int ey[KPT];
    #pragma unroll
    for (int k = 0; k < KPT; ++k) {
        int i = base + k * 256 + t;
        packed[k] = -1;
        ey[k] = 0;
        if (i < ng) {
            int4 q = ((const int4*)guide)[i];
            int c;
            int b = bucket_of(q, &c);
            int lr = atomicAdd(&hist[b], 1);
            packed[k] = (b << 13) | lr;
            ey[k] = (q.y + 1) | ((q.z + 1) << 9) | ((q.w + 1) << 18);
        }
    }
    __syncthreads();
    for (int i = t; i < NB; i += 256) {     // flush: hist[b] becomes global base
        int h = hist[i];
        hist[i] = h ? atomicAdd(&cursor[i], h) : 0;
    }
    __syncthreads();
    #pragma unroll
    for (int k = 0; k < KPT; ++k) {
        if (packed[k] >= 0) {
            int b  = packed[k] >> 13;
            int lr = packed[k] & 8191;
            int i  = base + k * 256 + t;
            int2 e;
            e.x = i | ((b & 7) << 24);
            e.y = ey[k];
            sorted[hist[b] + lr] = e;
        }
    }
}

// probe both rounds for one tile entry; inadmissible/miss -> -1
__device__ __forceinline__ void probe2(const int* __restrict__ table, int2 s2,
                                       int quad, int* o0, int* o1, int* oc) {
    int c = (__builtin_amdgcn_readfirstlane(s2.x) >> 24) & 7;
    int qx = (s2.y & 511) - 1;
    int qy = ((s2.y >> 9) & 511) - 1;
    int qz = ((s2.y >> 18) & 511) - 1;
    int res[2];
    #pragma unroll
    for (int r = 0; r < 2; ++r) {
        int sub = quad + r * 4;
        int offx = (c & 1) ? ((sub & 1) ? 1 : -1) : 0;
        int offy = (c & 2) ? ((sub & 2) ? 1 : -1) : 0;
        int offz = (c & 4) ? ((sub & 4) ? 1 : -1) : 0;
        int px = qx - offx, py = qy - offy, pz = qz - offz;
        bool valid = (s2.x >= 0) & ((sub & ~c & 7) == 0) &
                     ((unsigned)px < 256u) & ((unsigned)py < 256u) & ((unsigned)pz < 256u);
        int lin = (px >> 1) | ((py >> 1) << 7) | ((pz >> 1) << 14);
        int v = table[valid ? lin : 0];
        res[r] = valid ? v : -1;
    }
    *o0 = res[0]; *o1 = res[1]; *oc = c;
}

template<int USEFB>
__device__ __forceinline__ void loadA(const float* __restrict__ feats,
                                      const unsigned short* __restrict__ fb,
                                      int hidx, int quad, short8* a0, short8* a1) {
    short8 z = {0,0,0,0,0,0,0,0};
    *a0 = z; *a1 = z;
    if (hidx >= 0) {
        if constexpr (USEFB) {
            const unsigned short* fp = fb + (size_t)hidx * NIN + quad * 8;
            *a0 = *(const short8*)fp;
            *a1 = *(const short8*)(fp + 32);
        } else {
            const float4* fp = (const float4*)(feats + (size_t)hidx * NIN + quad * 8);
            float4 fA = fp[0], fB = fp[1];
            const float4* fp2 = (const float4*)(feats + (size_t)hidx * NIN + 32 + quad * 8);
            float4 fC = fp2[0], fD = fp2[1];
            short8 x, y;
            x[0] = (short)bf16rne(fA.x); x[1] = (short)bf16rne(fA.y);
            x[2] = (short)bf16rne(fA.z); x[3] = (short)bf16rne(fA.w);
            x[4] = (short)bf16rne(fB.x); x[5] = (short)bf16rne(fB.y);
            x[6] = (short)bf16rne(fB.z); x[7] = (short)bf16rne(fB.w);
            y[0] = (short)bf16rne(fC.x); y[1] = (short)bf16rne(fC.y);
            y[2] = (short)bf16rne(fC.z); y[3] = (short)bf16rne(fC.w);
            y[4] = (short)bf16rne(fD.x); y[5] = (short)bf16rne(fD.y);
            y[6] = (short)bf16rne(fD.z); y[7] = (short)bf16rne(fD.w);
            *a0 = x; *a1 = y;
        }
    }
}

__device__ __forceinline__ void slotMM(const unsigned short* __restrict__ wt,
                                       int c, int sub, int m, int quad,
                                       short8 a0, short8 a1,
                                       float4v* acc0, float4v* acc1) {
    int offx = (c & 1) ? ((sub & 1) ? 1 : -1) : 0;
    int offy = (c & 2) ? ((sub & 2) ? 1 : -1) : 0;
    int offz = (c & 4) ? ((sub & 4) ? 1 : -1) : 0;
    int oi = (offx + 1) * 9 + (offy + 1) * 3 + (offz + 1);
    const unsigned short* wb = wt + oi * 2048 + m * 64 + quad * 8;
    short8 b00 = *(const short8*)(wb);               // k<32,  ch m
    short8 b01 = *(const short8*)(wb + 1024);        // k<32,  ch 16+m
    short8 b10 = *(const short8*)(wb + 32);          // k>=32, ch m
    short8 b11 = *(const short8*)(wb + 1024 + 32);   // k>=32, ch 16+m
    *acc0 = __builtin_amdgcn_mfma_f32_16x16x32_bf16(a0, b00, *acc0, 0, 0, 0);
    *acc0 = __builtin_amdgcn_mfma_f32_16x16x32_bf16(a1, b10, *acc0, 0, 0, 0);
    *acc1 = __builtin_amdgcn_mfma_f32_16x16x32_bf16(a0, b01, *acc1, 0, 0, 0);
    *acc1 = __builtin_amdgcn_mfma_f32_16x16x32_bf16(a1, b11, *acc1, 0, 0, 0);
}

// ---- main: each wave owns NT consecutive 16-row tiles (uniform class per tile,
// spatially bucketed). Per-tile chain {sorted -> probe -> shfl -> gather -> MFMA ->
// store} is software-pipelined across tiles. ----
template<int USEFB>
__launch_bounds__(256, 4)
__global__ void gen_conv(const float* __restrict__ feats,        // [Np,64] fp32
                         const unsigned short* __restrict__ fb,  // [Np,64] bf16
                         const float* __restrict__ bias,         // [32]
                         const int* __restrict__ table,          // [2^21]
                         const int2* __restrict__ sorted,        // padded, w/ coords
                         const int* __restrict__ totalp,         // [1]
                         const unsigned short* __restrict__ wt,  // [27][32][64] bf16
                         float* __restrict__ out) {
    // bijective XCD swizzle: consecutive tiles stay on one XCD's L2
    int nwg = gridDim.x;
    int orig = blockIdx.x;
    int qd = nwg >> 3, rd = nwg & 7;
    int xc = orig & 7, ix = orig >> 3;
    int wg = (xc < rd ? xc * (qd + 1) : rd * (qd + 1) + (xc - rd) * qd) + ix;

    int wave = wg * 4 + (threadIdx.x >> 6);
    int lane = threadIdx.x & 63;
    int m    = lane & 15;          // guide-row in tile / B n-col
    int quad = lane >> 4;          // k-octet / probe slot base

    int ntile = totalp[0] >> 4;    // total is 16-aligned
    int t0 = wave * NT;
    if (t0 >= ntile) return;
    int tend = t0 + NT; if (tend > ntile) tend = ntile;

    float bv0 = bias[m], bv1 = bias[16 + m];

    // prologue: stage tile t0
    int2 s2 = sorted[t0 * 16 + m];
    int idx0, idx1, cc;
    probe2(table, s2, quad, &idx0, &idx1, &cc);

    for (int t = t0; t < tend; ++t) {
        bool more = (t + 1 < tend);
        int2 s2n = s2;
        if (more) s2n = sorted[(t + 1) * 16 + m];   // issue early

        int c = cc;
        int id = (s2.x < 0) ? -1 : (s2.x & 0xffffff);

        // per-slot gathered row indices (slot s covers rows via lane group s&3)
        int h0 = __shfl(idx0, m, 64);
        int h1 = __shfl(idx0, 16 + m, 64);
        int h2 = __shfl(idx0, 32 + m, 64);
        int h3 = __shfl(idx0, 48 + m, 64);
        int h4 = __shfl(idx1, m, 64);
        int h5 = __shfl(idx1, 16 + m, 64);
        int h6 = __shfl(idx1, 32 + m, 64);
        int h7 = __shfl(idx1, 48 + m, 64);

        float4v acc0 = {0.f, 0.f, 0.f, 0.f};
        float4v acc1 = {0.f, 0.f, 0.f, 0.f};

        // half 1: slots 0..3 — batch A gathers, then B+MFMA
        short8 a00, a01, a10, a11, a20, a21, a30, a31;
        loadA<USEFB>(feats, fb, h0, quad, &a00, &a01);
        loadA<USEFB>(feats, fb, h1, quad, &a10, &a11);
        loadA<USEFB>(feats, fb, h2, quad, &a20, &a21);
        loadA<USEFB>(feats, fb, h3, quad, &a30, &a31);
        slotMM(wt, c, 0, m, quad, a00, a01, &acc0, &acc1);
        slotMM(wt, c, 1, m, quad, a10, a11, &acc0, &acc1);
        slotMM(wt, c, 2, m, quad, a20, a21, &acc0, &acc1);
        slotMM(wt, c, 3, m, quad, a30, a31, &acc0, &acc1);

        // half 2: slots 4..7
        short8 a40, a41, a50, a51, a60, a61, a70, a71;
        loadA<USEFB>(feats, fb, h4, quad, &a40, &a41);
        loadA<USEFB>(feats, fb, h5, quad, &a50, &a51);
        loadA<USEFB>(feats, fb, h6, quad, &a60, &a61);
        loadA<USEFB>(feats, fb, h7, quad, &a70, &a71);
        slotMM(wt, c, 4, m, quad, a40, a41, &acc0, &acc1);
        slotMM(wt, c, 5, m, quad, a50, a51, &acc0, &acc1);
        slotMM(wt, c, 6, m, quad, a60, a61, &acc0, &acc1);
        slotMM(wt, c, 7, m, quad, a70, a71, &acc0, &acc1);

        // next-tile probes: issued as the LAST loads of the iteration so MFMA
        // waits (through their own B loads) leave these in flight
        int nidx0 = idx0, nidx1 = idx1, ncc = cc;
        if (more) probe2(table, s2n, quad, &nidx0, &nidx1, &ncc);

        // existence + stores: lane's col n=m; rows mr=quad*4+r
        unsigned long long eb = __ballot(idx0 >= 0) | __ballot(idx1 >= 0);
        unsigned e16 = (unsigned)((eb | (eb >> 16) | (eb >> 32) | (eb >> 48)) & 0xffffull);
        #pragma unroll
        for (int r = 0; r < 4; ++r) {
            int mr = quad * 4 + r;
            int idr = __shfl(id, mr, 64);
            if (idr >= 0) {
                bool exr = (e16 >> mr) & 1;
                out[(size_t)idr * NOUT + m]      = exr ? (acc0[r] + bv0) : 0.f;
                out[(size_t)idr * NOUT + 16 + m] = exr ? (acc1[r] + bv1) : 0.f;
            }
        }

        s2 = s2n; idx0 = nidx0; idx1 = nidx1; cc = ncc;
    }
}

extern "C" void kernel_launch(void* const* d_in, const int* in_sizes, int n_in,
                              void* d_out, int out_size, void* d_ws, size_t ws_size,
                              hipStream_t stream) {
    const float* feats   = (const float*)d_in[0];
    const float* weights = (const float*)d_in[1];
    const float* bias    = (const float*)d_in[2];
    const int*   coords  = (const int*)d_in[3];
    const int*   guide   = (const int*)d_in[4];
    float* out = (float*)d_out;

    int np = in_sizes[3] / 4;
    int ng = in_sizes[4] / 4;

    int* wsI = (int*)d_ws;
    int SC = (ng + NB * 16 + 3) & ~3;        // bucketed capacity (entries)
    int A = TSIZE + 2 * SC;                  // sorted is int2
    int* table   = wsI;                      // 2^21
    int2* sorted = (int2*)(wsI + TSIZE);     // SC entries, -1 padded
    int* count   = wsI + A;                  // NB
    int* cursor  = wsI + A + NB;             // NB
    int* total   = wsI + A + 2 * NB;         // 1 (+3 pad)
    unsigned short* wt = (unsigned short*)(wsI + A + 2 * NB + 4);   // 27*32*64 bf16
    unsigned short* fb = (unsigned short*)(wsI + A + 2 * NB + 4 + 27648);
    size_t need = ((size_t)A + 2 * NB + 4 + 27648) * 4 + (size_t)np * NIN * 2;
    int usefb = (ws_size >= need) ? 1 : 0;

    int n4 = A / 4;
    int fn4 = usefb ? np * (NIN / 4) : 0;
    int prep_n = n4 > fn4 ? n4 : fn4;
    if (prep_n < 27 * 64 * 32) prep_n = 27 * 64 * 32;
    hipLaunchKernelGGL(prep, dim3((prep_n + 255) / 256), dim3(256), 0, stream,
                       (int4*)wsI, n4, (int4*)count, weights, wt, feats, fb, fn4);

    int bcb1 = (np + 255) / 256;
    int bcb2 = (ng + CHUNK - 1) / CHUNK;
    int bc_blocks = bcb1 > bcb2 ? bcb1 : bcb2;
    hipLaunchKernelGGL(bc, dim3(bc_blocks), dim3(256), 0, stream,
                       coords, np, table, guide, ng, count);

    hipLaunchKernelGGL(scanB, dim3(1), dim3(128), 0, stream, count, cursor, total);

    hipLaunchKernelGGL(scat, dim3((ng + CHUNK - 1) / CHUNK), dim3(256), 0, stream,
                       guide, ng, cursor, sorted);

    int maxtiles = (ng + NB * 15 + 15) / 16;
    int blocks = (maxtiles + NT * 4 - 1) / (NT * 4);   // 4 waves/block, NT tiles/wave
    if (usefb) {
        hipLaunchKernelGGL((gen_conv<1>), dim3(blocks), dim3(256), 0, stream,
                           feats, fb, bias, table, sorted, total, wt, out);
    } else {
        hipLaunchKernelGGL((gen_conv<0>), dim3(blocks), dim3(256), 0, stream,
                           feats, fb, bias, table, sorted, total, wt, out);
    }
}

// Round 6
// 178.065 us; speedup vs baseline: 2.7248x; 1.4134x over previous
//
#include <hip/hip_runtime.h>

#define NIN 64
#define NOUT 32
#define TBITS 21                 // 128^3 stride-2 lattice
#define TSIZE (1 << TBITS)
#define NB 512                   // class-major: 8 classes x 64 spatial cells (64^3)
#define CHUNK 4096               // guides per block in bc/scat
#define KPT (CHUNK / 256)
#define BLKG 128                 // guides per gen_conv block = 4 waves x 2 tiles x 16

typedef __attribute__((ext_vector_type(8))) short short8;
typedef __attribute__((ext_vector_type(4))) float float4v;
typedef __attribute__((ext_vector_type(4))) unsigned short ushort4v;

__device__ __forceinline__ unsigned short bf16rne(float x) {
    unsigned u = __float_as_uint(x);
    u += 0x7fffu + ((u >> 16) & 1u);
    return (unsigned short)(u >> 16);
}

// class-major bucket: all guides of one parity class contiguous, spatially sorted
__device__ __forceinline__ int bucket_of(int4 q, int* cls) {
    int c = (q.y & 1) | ((q.z & 1) << 1) | ((q.w & 1) << 2);
    *cls = c;
    int sp = ((q.y >> 6) & 3) | (((q.z >> 6) & 3) << 2) | (((q.w >> 6) & 3) << 4);
    return (c << 6) | sp;
}

// ws (ints): [0,TSIZE) table | [TSIZE, A) sorted int2 (-1 padded) |
//   A: count[512] | cursor[512] at A+512 | classbase[16] at A+1024 |
//   wt bf16 [27][32][64] at A+1040 | fb bf16 [Np][64] after wt
__global__ void prep(int4* __restrict__ ws4, int n4,
                     int4* __restrict__ count4,
                     const float* __restrict__ w, unsigned short* __restrict__ wt,
                     const float* __restrict__ f, unsigned short* __restrict__ fb,
                     int fn4) {
    int i = blockIdx.x * blockDim.x + threadIdx.x;
    if (i < n4) ws4[i] = make_int4(-1, -1, -1, -1);
    if (i < NB / 4) count4[i] = make_int4(0, 0, 0, 0);
    if (i < 27 * 64 * 32) {          // fp32 [27][64][32] -> bf16 [27][32][64]
        int oi = i >> 11;
        int k  = (i >> 5) & 63;
        int ch = i & 31;
        wt[oi * 2048 + ch * 64 + k] = bf16rne(w[i]);
    }
    if (i < fn4) {
        float4 v = ((const float4*)f)[i];
        ushort4v o;
        o.x = bf16rne(v.x); o.y = bf16rne(v.y);
        o.z = bf16rne(v.z); o.w = bf16rne(v.w);
        ((ushort4v*)fb)[i] = o;
    }
}

// hash table build + chunked LDS-histogram bucket count
__global__ void bc(const int* __restrict__ coords, int np, int* __restrict__ table,
                   const int* __restrict__ guide, int ng, int* __restrict__ count) {
    __shared__ int hist[NB];
    for (int i = threadIdx.x; i < NB; i += blockDim.x) hist[i] = 0;
    int gi = blockIdx.x * blockDim.x + threadIdx.x;
    if (gi < np) {
        int x = coords[gi * 4 + 1];
        int y = coords[gi * 4 + 2];
        int z = coords[gi * 4 + 3];
        table[(x >> 1) | ((y >> 1) << 7) | ((z >> 1) << 14)] = gi;
    }
    __syncthreads();
    int base = blockIdx.x * CHUNK;
    if (base < ng) {
        int end = base + CHUNK; if (end > ng) end = ng;
        for (int i = base + threadIdx.x; i < end; i += blockDim.x) {
            int c;
            int b = bucket_of(((const int4*)guide)[i], &c);
            atomicAdd(&hist[b], 1);
        }
        __syncthreads();
        for (int i = threadIdx.x; i < NB; i += blockDim.x)
            if (hist[i]) atomicAdd(&count[i], hist[i]);
    }
}

// scan over 512 class-major buckets; per-CLASS totals padded to BLKG so every
// gen_conv block is class-uniform. cursor = bucket write base; classbase[9].
__global__ void scanB(const int* __restrict__ count, int* __restrict__ cursor,
                      int* __restrict__ classbase) {
    __shared__ int ps[512];
    __shared__ int cb[9];
    int t = threadIdx.x;
    int v = count[t];
    ps[t] = v;
    __syncthreads();
    #pragma unroll
    for (int off = 1; off < 512; off <<= 1) {
        int val = ps[t];
        int u = (t >= off) ? ps[t - off] : 0;
        __syncthreads();
        ps[t] = val + u;
        __syncthreads();
    }
    int incl = ps[t];
    if (t == 0) {
        int base = 0;
        #pragma unroll
        for (int cc = 0; cc < 8; ++cc) {
            cb[cc] = base;
            int hi = ps[cc * 64 + 63];
            int lo = cc ? ps[cc * 64 - 1] : 0;
            base += (hi - lo + BLKG - 1) & ~(BLKG - 1);
        }
        cb[8] = base;
        for (int j = 0; j < 9; ++j) classbase[j] = cb[j];
    }
    __syncthreads();
    int cc = t >> 6;
    int lo = cc ? ps[cc * 64 - 1] : 0;
    cursor[t] = cb[cc] + (incl - v) - lo;
}

// chunked scatter; entry = {id | class<<24, x+1 | y+1<<9 | z+1<<18}
__global__ void scat(const int* __restrict__ guide, int ng,
                     int* __restrict__ cursor, int2* __restrict__ sorted) {
    __shared__ int hist[NB];
    int t = threadIdx.x;
    for (int i = t; i < NB; i += 256) hist[i] = 0;
    __syncthreads();
    int base = blockIdx.x * CHUNK;
    int packed[KPT];                 // (bucket<<13) | lrank, or -1
    int ey[KPT];
    #pragma unroll
    for (int k = 0; k < KPT; ++k) {
        int i = base + k * 256 + t;
        packed[k] = -1;
        ey[k] = 0;
        if (i < ng) {
            int4 q = ((const int4*)guide)[i];
            int c;
            int b = bucket_of(q, &c);
            int lr = atomicAdd(&hist[b], 1);
            packed[k] = (b << 13) | lr;
            ey[k] = (q.y + 1) | ((q.z + 1) << 9) | ((q.w + 1) << 18);
        }
    }
    __syncthreads();
    for (int i = t; i < NB; i += 256) {
        int h = hist[i];
        hist[i] = h ? atomicAdd(&cursor[i], h) : 0;
    }
    __syncthreads();
    #pragma unroll
    for (int k = 0; k < KPT; ++k) {
        if (packed[k] >= 0) {
            int b  = packed[k] >> 13;
            int lr = packed[k] & 8191;
            int i  = base + k * 256 + t;
            int2 e;
            e.x = i | ((b >> 6) << 24);     // class = bucket>>6 (class-major)
            e.y = ey[k];
            sorted[hist[b] + lr] = e;
        }
    }
}

// ---------------- gen_conv helpers (class templated) ----------------

template<int C>
__device__ __forceinline__ void probe2t(const int* __restrict__ table, int2 s2,
                                        int quad, int* o0, int* o1) {
    int qx = (s2.y & 511) - 1;
    int qy = ((s2.y >> 9) & 511) - 1;
    int qz = ((s2.y >> 18) & 511) - 1;
    int res[2];
    #pragma unroll
    for (int r = 0; r < 2; ++r) {
        int sub = quad + r * 4;
        int offx = (C & 1) ? ((sub & 1) ? 1 : -1) : 0;
        int offy = (C & 2) ? ((sub & 2) ? 1 : -1) : 0;
        int offz = (C & 4) ? ((sub & 4) ? 1 : -1) : 0;
        int px = qx - offx, py = qy - offy, pz = qz - offz;
        bool valid = (s2.x >= 0) & ((sub & ~C & 7) == 0) &
                     ((unsigned)px < 256u) & ((unsigned)py < 256u) & ((unsigned)pz < 256u);
        int lin = (px >> 1) | ((py >> 1) << 7) | ((pz >> 1) << 14);
        int v = table[valid ? lin : 0];
        res[r] = valid ? v : -1;
    }
    *o0 = res[0]; *o1 = res[1];
}

// stage wt[oi(C,SUB)] into LDS slot SUB with XOR swizzle; 1x16B per thread
template<int C, int SUB>
__device__ __forceinline__ void stage_sub(const unsigned short* __restrict__ wt,
                                          unsigned short* bshr, int m, int j) {
    if constexpr ((SUB & ~C & 7) == 0) {
        constexpr int offx = (C & 1) ? ((SUB & 1) ? 1 : -1) : 0;
        constexpr int offy = (C & 2) ? ((SUB & 2) ? 1 : -1) : 0;
        constexpr int offz = (C & 4) ? ((SUB & 4) ? 1 : -1) : 0;
        constexpr int oi = (offx + 1) * 9 + (offy + 1) * 3 + (offz + 1);
        short8 v = *(const short8*)(wt + oi * 2048 + m * 64 + j * 8);
        *(short8*)((char*)bshr + SUB * 4096 + m * 128 + ((j ^ (m & 7)) << 4)) = v;
    }
}

template<int USEFB, int C, int SUB>
__device__ __forceinline__ void slot_load(const float* __restrict__ feats,
                                          const unsigned short* __restrict__ fb,
                                          int idx0, int idx1,
                                          unsigned long long bal0, unsigned long long bal1,
                                          int m, int quad, short8* A0, short8* A1) {
    if constexpr ((SUB & ~C & 7) == 0) {
        unsigned long long bal = (SUB < 4) ? bal0 : bal1;
        unsigned rowm = (unsigned)((bal >> ((SUB & 3) * 16)) & 0xffffull);
        short8 z = {0,0,0,0,0,0,0,0};
        A0[SUB] = z; A1[SUB] = z;
        if (rowm) {                      // wave-uniform branch
            int h = __shfl((SUB < 4) ? idx0 : idx1, (SUB & 3) * 16 + m, 64);
            if (h >= 0) {
                if constexpr (USEFB) {
                    const unsigned short* fp = fb + (size_t)h * NIN + quad * 8;
                    A0[SUB] = *(const short8*)fp;
                    A1[SUB] = *(const short8*)(fp + 32);
                } else {
                    const float4* fp = (const float4*)(feats + (size_t)h * NIN + quad * 8);
                    float4 fA = fp[0], fB = fp[1];
                    const float4* fp2 = (const float4*)(feats + (size_t)h * NIN + 32 + quad * 8);
                    float4 fC = fp2[0], fD = fp2[1];
                    short8 x, y;
                    x[0] = (short)bf16rne(fA.x); x[1] = (short)bf16rne(fA.y);
                    x[2] = (short)bf16rne(fA.z); x[3] = (short)bf16rne(fA.w);
                    x[4] = (short)bf16rne(fB.x); x[5] = (short)bf16rne(fB.y);
                    x[6] = (short)bf16rne(fB.z); x[7] = (short)bf16rne(fB.w);
                    y[0] = (short)bf16rne(fC.x); y[1] = (short)bf16rne(fC.y);
                    y[2] = (short)bf16rne(fC.z); y[3] = (short)bf16rne(fC.w);
                    y[4] = (short)bf16rne(fD.x); y[5] = (short)bf16rne(fD.y);
                    y[6] = (short)bf16rne(fD.z); y[7] = (short)bf16rne(fD.w);
                    A0[SUB] = x; A1[SUB] = y;
                }
            }
        }
    }
}

template<int C, int SUB>
__device__ __forceinline__ void slot_mm(const unsigned short* bshr,
                                        unsigned long long bal0, unsigned long long bal1,
                                        int m, int quad, const short8* A0, const short8* A1,
                                        float4v* acc0, float4v* acc1) {
    if constexpr ((SUB & ~C & 7) == 0) {
        unsigned long long bal = (SUB < 4) ? bal0 : bal1;
        unsigned rowm = (unsigned)((bal >> ((SUB & 3) * 16)) & 0xffffull);
        if (rowm) {
            const char* base = (const char*)bshr + SUB * 4096;
            short8 b00 = *(const short8*)(base + m * 128 + ((quad ^ (m & 7)) << 4));
            short8 b10 = *(const short8*)(base + m * 128 + (((4 + quad) ^ (m & 7)) << 4));
            short8 b01 = *(const short8*)(base + (16 + m) * 128 + ((quad ^ ((16 + m) & 7)) << 4));
            short8 b11 = *(const short8*)(base + (16 + m) * 128 + (((4 + quad) ^ ((16 + m) & 7)) << 4));
            *acc0 = __builtin_amdgcn_mfma_f32_16x16x32_bf16(A0[SUB], b00, *acc0, 0, 0, 0);
            *acc0 = __builtin_amdgcn_mfma_f32_16x16x32_bf16(A1[SUB], b10, *acc0, 0, 0, 0);
            *acc1 = __builtin_amdgcn_mfma_f32_16x16x32_bf16(A0[SUB], b01, *acc1, 0, 0, 0);
            *acc1 = __builtin_amdgcn_mfma_f32_16x16x32_bf16(A1[SUB], b11, *acc1, 0, 0, 0);
        }
    }
}

template<int USEFB, int C>
__device__ __forceinline__ void conv_class(const float* __restrict__ feats,
                                           const unsigned short* __restrict__ fb,
                                           const float* __restrict__ bias,
                                           const int* __restrict__ table,
                                           const int2* __restrict__ sorted,
                                           const unsigned short* __restrict__ wt,
                                           float* __restrict__ out,
                                           int bt0, unsigned short* bshr) {
    int tid = threadIdx.x;
    {   // stage admissible B matrices (<=8 x 4KB) into LDS, swizzled
        int mm = tid >> 3, jj = tid & 7;
        stage_sub<C, 0>(wt, bshr, mm, jj);
        stage_sub<C, 1>(wt, bshr, mm, jj);
        stage_sub<C, 2>(wt, bshr, mm, jj);
        stage_sub<C, 3>(wt, bshr, mm, jj);
        stage_sub<C, 4>(wt, bshr, mm, jj);
        stage_sub<C, 5>(wt, bshr, mm, jj);
        stage_sub<C, 6>(wt, bshr, mm, jj);
        stage_sub<C, 7>(wt, bshr, mm, jj);
    }
    __syncthreads();

    int wid = tid >> 6, lane = tid & 63;
    int m = lane & 15, quad = lane >> 4;
    float bv0 = bias[m], bv1 = bias[16 + m];

    int t0 = bt0 + wid * 2;
    int2 s2 = sorted[t0 * 16 + m];
    int idx0, idx1;
    probe2t<C>(table, s2, quad, &idx0, &idx1);

    #pragma unroll
    for (int tt = 0; tt < 2; ++tt) {
        int t = t0 + tt;
        bool more = (tt == 0);
        int2 s2n = s2;
        if (more) s2n = sorted[(t + 1) * 16 + m];      // prefetch next tile meta

        int id = (s2.x < 0) ? -1 : (s2.x & 0xffffff);
        unsigned long long bal0 = __ballot(idx0 >= 0);
        unsigned long long bal1 = __ballot(idx1 >= 0);

        float4v acc0 = {0.f, 0.f, 0.f, 0.f};
        float4v acc1 = {0.f, 0.f, 0.f, 0.f};
        short8 A0[8], A1[8];

        // half 1: batched gathers then LDS-B MFMAs
        slot_load<USEFB, C, 0>(feats, fb, idx0, idx1, bal0, bal1, m, quad, A0, A1);
        slot_load<USEFB, C, 1>(feats, fb, idx0, idx1, bal0, bal1, m, quad, A0, A1);
        slot_load<USEFB, C, 2>(feats, fb, idx0, idx1, bal0, bal1, m, quad, A0, A1);
        slot_load<USEFB, C, 3>(feats, fb, idx0, idx1, bal0, bal1, m, quad, A0, A1);
        slot_mm<C, 0>(bshr, bal0, bal1, m, quad, A0, A1, &acc0, &acc1);
        slot_mm<C, 1>(bshr, bal0, bal1, m, quad, A0, A1, &acc0, &acc1);
        slot_mm<C, 2>(bshr, bal0, bal1, m, quad, A0, A1, &acc0, &acc1);
        slot_mm<C, 3>(bshr, bal0, bal1, m, quad, A0, A1, &acc0, &acc1);
        // half 2
        slot_load<USEFB, C, 4>(feats, fb, idx0, idx1, bal0, bal1, m, quad, A0, A1);
        slot_load<USEFB, C, 5>(feats, fb, idx0, idx1, bal0, bal1, m, quad, A0, A1);
        slot_load<USEFB, C, 6>(feats, fb, idx0, idx1, bal0, bal1, m, quad, A0, A1);
        slot_load<USEFB, C, 7>(feats, fb, idx0, idx1, bal0, bal1, m, quad, A0, A1);
        slot_mm<C, 4>(bshr, bal0, bal1, m, quad, A0, A1, &acc0, &acc1);
        slot_mm<C, 5>(bshr, bal0, bal1, m, quad, A0, A1, &acc0, &acc1);
        slot_mm<C, 6>(bshr, bal0, bal1, m, quad, A0, A1, &acc0, &acc1);
        slot_mm<C, 7>(bshr, bal0, bal1, m, quad, A0, A1, &acc0, &acc1);

        // next-tile probes issued after this tile's loads (stay in flight)
        int nidx0 = idx0, nidx1 = idx1;
        if (more) probe2t<C>(table, s2n, quad, &nidx0, &nidx1);

        unsigned long long eb = bal0 | bal1;
        unsigned e16 = (unsigned)((eb | (eb >> 16) | (eb >> 32) | (eb >> 48)) & 0xffffull);
        #pragma unroll
        for (int r = 0; r < 4; ++r) {
            int mr = quad * 4 + r;
            int idr = __shfl(id, mr, 64);
            if (idr >= 0) {
                bool exr = (e16 >> mr) & 1;
                out[(size_t)idr * NOUT + m]      = exr ? (acc0[r] + bv0) : 0.f;
                out[(size_t)idr * NOUT + 16 + m] = exr ? (acc1[r] + bv1) : 0.f;
            }
        }

        s2 = s2n; idx0 = nidx0; idx1 = nidx1;
    }
}

template<int USEFB>
__launch_bounds__(256, 4)
__global__ void gen_conv(const float* __restrict__ feats,
                         const unsigned short* __restrict__ fb,
                         const float* __restrict__ bias,
                         const int* __restrict__ table,
                         const int2* __restrict__ sorted,
                         const int* __restrict__ classbase,   // [9], BLKG-aligned
                         const unsigned short* __restrict__ wt,
                         float* __restrict__ out) {
    __shared__ unsigned short bshr[16384];                     // 32 KB

    int nwg = gridDim.x;
    int orig = blockIdx.x;
    int qd = nwg >> 3, rd = nwg & 7;
    int xc = orig & 7, ix = orig >> 3;
    int wg = (xc < rd ? xc * (qd + 1) : rd * (qd + 1) + (xc - rd) * qd) + ix;

    int g0 = wg * BLKG;                 // block's first guide slot
    if (g0 >= classbase[8]) return;     // uniform exit
    int c = 0;
    #pragma unroll
    for (int j = 1; j < 8; ++j) c += (g0 >= classbase[j]) ? 1 : 0;
    c = __builtin_amdgcn_readfirstlane(c);
    int bt0 = wg * (BLKG / 16);         // first tile

    switch (c) {
        case 0: conv_class<USEFB, 0>(feats, fb, bias, table, sorted, wt, out, bt0, bshr); break;
        case 1: conv_class<USEFB, 1>(feats, fb, bias, table, sorted, wt, out, bt0, bshr); break;
        case 2: conv_class<USEFB, 2>(feats, fb, bias, table, sorted, wt, out, bt0, bshr); break;
        case 3: conv_class<USEFB, 3>(feats, fb, bias, table, sorted, wt, out, bt0, bshr); break;
        case 4: conv_class<USEFB, 4>(feats, fb, bias, table, sorted, wt, out, bt0, bshr); break;
        case 5: conv_class<USEFB, 5>(feats, fb, bias, table, sorted, wt, out, bt0, bshr); break;
        case 6: conv_class<USEFB, 6>(feats, fb, bias, table, sorted, wt, out, bt0, bshr); break;
        case 7: conv_class<USEFB, 7>(feats, fb, bias, table, sorted, wt, out, bt0, bshr); break;
    }
}

extern "C" void kernel_launch(void* const* d_in, const int* in_sizes, int n_in,
                              void* d_out, int out_size, void* d_ws, size_t ws_size,
                              hipStream_t stream) {
    const float* feats   = (const float*)d_in[0];
    const float* weights = (const float*)d_in[1];
    const float* bias    = (const float*)d_in[2];
    const int*   coords  = (const int*)d_in[3];
    const int*   guide   = (const int*)d_in[4];
    float* out = (float*)d_out;

    int np = in_sizes[3] / 4;
    int ng = in_sizes[4] / 4;

    int* wsI = (int*)d_ws;
    int SC = (ng + 8 * BLKG + 3) & ~3;       // sorted capacity (entries)
    int A = TSIZE + 2 * SC;                  // sorted is int2
    int* table     = wsI;                    // 2^21
    int2* sorted   = (int2*)(wsI + TSIZE);   // SC entries, -1 padded
    int* count     = wsI + A;                // 512
    int* cursor    = wsI + A + 512;          // 512
    int* classbase = wsI + A + 1024;         // 9 (+pad to 16)
    unsigned short* wt = (unsigned short*)(wsI + A + 1040);   // 27*32*64 bf16
    unsigned short* fb = (unsigned short*)(wsI + A + 1040 + 27648);
    size_t need = ((size_t)A + 1040 + 27648) * 4 + (size_t)np * NIN * 2;
    int usefb = (ws_size >= need) ? 1 : 0;

    int n4 = A / 4;
    int fn4 = usefb ? np * (NIN / 4) : 0;
    int prep_n = n4 > fn4 ? n4 : fn4;
    if (prep_n < 27 * 64 * 32) prep_n = 27 * 64 * 32;
    hipLaunchKernelGGL(prep, dim3((prep_n + 255) / 256), dim3(256), 0, stream,
                       (int4*)wsI, n4, (int4*)count, weights, wt, feats, fb, fn4);

    int bcb1 = (np + 255) / 256;
    int bcb2 = (ng + CHUNK - 1) / CHUNK;
    int bc_blocks = bcb1 > bcb2 ? bcb1 : bcb2;
    hipLaunchKernelGGL(bc, dim3(bc_blocks), dim3(256), 0, stream,
                       coords, np, table, guide, ng, count);

    hipLaunchKernelGGL(scanB, dim3(1), dim3(512), 0, stream, count, cursor, classbase);

    hipLaunchKernelGGL(scat, dim3((ng + CHUNK - 1) / CHUNK), dim3(256), 0, stream,
                       guide, ng, cursor, sorted);

    int maxguides = ng + 8 * (BLKG - 1);
    int blocks = (maxguides + BLKG - 1) / BLKG;
    if (usefb) {
        hipLaunchKernelGGL((gen_conv<1>), dim3(blocks), dim3(256), 0, stream,
                           feats, fb, bias, table, sorted, classbase, wt, out);
    } else {
        hipLaunchKernelGGL((gen_conv<0>), dim3(blocks), dim3(256), 0, stream,
                           feats, fb, bias, table, sorted, classbase, wt, out);
    }
}

// Round 7
// 172.079 us; speedup vs baseline: 2.8196x; 1.0348x over previous
//
#include <hip/hip_runtime.h>

#define NIN 64
#define NOUT 32
#define TBITS 21                 // 128^3 stride-2 lattice
#define TSIZE (1 << TBITS)
#define NB 512                   // class-major: 8 classes x 64 spatial cells (64^3)
#define CHUNK 4096               // guides per block in prep-count/scat
#define KPT (CHUNK / 256)
#define BLKG 128                 // guides per gen_conv block = 4 waves x 2 tiles x 16

typedef __attribute__((ext_vector_type(8))) short short8;
typedef __attribute__((ext_vector_type(4))) float float4v;
typedef __attribute__((ext_vector_type(4))) unsigned short ushort4v;

__device__ __forceinline__ unsigned short bf16rne(float x) {
    unsigned u = __float_as_uint(x);
    u += 0x7fffu + ((u >> 16) & 1u);
    return (unsigned short)(u >> 16);
}

constexpr int popc8(int x) { int n = 0; for (int i = 0; i < 8; ++i) n += (x >> i) & 1; return n; }
constexpr int nth_sub(int C, int r) {
    int cnt = 0;
    for (int s = 0; s < 8; ++s)
        if ((s & ~C & 7) == 0) { if (cnt == r) return s; ++cnt; }
    return 0;
}

// class-major bucket: all guides of one parity class contiguous, spatially sorted
__device__ __forceinline__ int bucket_of(int4 q, int* cls) {
    int c = (q.y & 1) | ((q.z & 1) << 1) | ((q.w & 1) << 2);
    *cls = c;
    int sp = ((q.y >> 6) & 3) | (((q.z >> 6) & 3) << 2) | (((q.w >> 6) & 3) << 4);
    return (c << 6) | sp;
}

// ws (ints): [0,TSIZE) table | [TSIZE, A) sorted int2 (-1 padded) |
//   A: count[512] | cursor[512] at A+512 | classbase[16] at A+1024 |
//   wt bf16 [27][32][64] at A+1040 | fb bf16 [Np][64] after wt
// prep: init table+sorted, wt/fb convert, bucket count (count[] pre-zeroed by memset)
__global__ void prep(int4* __restrict__ ws4, int n4,
                     const float* __restrict__ w, unsigned short* __restrict__ wt,
                     const float* __restrict__ f, unsigned short* __restrict__ fb,
                     int fn4,
                     const int* __restrict__ guide, int ng, int* __restrict__ count) {
    __shared__ int hist[NB];
    int i = blockIdx.x * blockDim.x + threadIdx.x;
    if (i < n4) ws4[i] = make_int4(-1, -1, -1, -1);
    if (i < 27 * 64 * 32) {          // fp32 [27][64][32] -> bf16 [27][32][64]
        int oi = i >> 11;
        int k  = (i >> 5) & 63;
        int ch = i & 31;
        wt[oi * 2048 + ch * 64 + k] = bf16rne(w[i]);
    }
    if (i < fn4) {
        float4 v = ((const float4*)f)[i];
        ushort4v o;
        o.x = bf16rne(v.x); o.y = bf16rne(v.y);
        o.z = bf16rne(v.z); o.w = bf16rne(v.w);
        ((ushort4v*)fb)[i] = o;
    }
    int base = blockIdx.x * CHUNK;
    if (base < ng) {
        for (int j = threadIdx.x; j < NB; j += 256) hist[j] = 0;
        __syncthreads();
        int end = base + CHUNK; if (end > ng) end = ng;
        for (int j = base + threadIdx.x; j < end; j += 256) {
            int c;
            int b = bucket_of(((const int4*)guide)[j], &c);
            atomicAdd(&hist[b], 1);
        }
        __syncthreads();
        for (int j = threadIdx.x; j < NB; j += 256)
            if (hist[j]) atomicAdd(&count[j], hist[j]);
    }
}

// scan over 512 class-major buckets; per-CLASS totals padded to BLKG so every
// gen_conv block is class-uniform. cursor = bucket write base; classbase[9].
__global__ void scanB(const int* __restrict__ count, int* __restrict__ cursor,
                      int* __restrict__ classbase) {
    __shared__ int ps[512];
    __shared__ int cb[9];
    int t = threadIdx.x;
    int v = count[t];
    ps[t] = v;
    __syncthreads();
    #pragma unroll
    for (int off = 1; off < 512; off <<= 1) {
        int val = ps[t];
        int u = (t >= off) ? ps[t - off] : 0;
        __syncthreads();
        ps[t] = val + u;
        __syncthreads();
    }
    int incl = ps[t];
    if (t == 0) {
        int base = 0;
        #pragma unroll
        for (int cc = 0; cc < 8; ++cc) {
            cb[cc] = base;
            int hi = ps[cc * 64 + 63];
            int lo = cc ? ps[cc * 64 - 1] : 0;
            base += (hi - lo + BLKG - 1) & ~(BLKG - 1);
        }
        cb[8] = base;
        for (int j = 0; j < 9; ++j) classbase[j] = cb[j];
    }
    __syncthreads();
    int cc = t >> 6;
    int lo = cc ? ps[cc * 64 - 1] : 0;
    cursor[t] = cb[cc] + (incl - v) - lo;
}

// table build + chunked scatter; entry = {id | class<<24, x+1 | y+1<<9 | z+1<<18}
__global__ void scat(const int* __restrict__ coords, int np, int* __restrict__ table,
                     const int* __restrict__ guide, int ng,
                     int* __restrict__ cursor, int2* __restrict__ sorted) {
    int gi = blockIdx.x * blockDim.x + threadIdx.x;
    if (gi < np) {
        int x = coords[gi * 4 + 1];
        int y = coords[gi * 4 + 2];
        int z = coords[gi * 4 + 3];
        table[(x >> 1) | ((y >> 1) << 7) | ((z >> 1) << 14)] = gi;
    }
    __shared__ int hist[NB];
    int t = threadIdx.x;
    int base = blockIdx.x * CHUNK;
    if (base >= ng) return;
    for (int i = t; i < NB; i += 256) hist[i] = 0;
    __syncthreads();
    int packed[KPT];                 // (bucket<<13) | lrank, or -1
    int ey[KPT];
    #pragma unroll
    for (int k = 0; k < KPT; ++k) {
        int i = base + k * 256 + t;
        packed[k] = -1;
        ey[k] = 0;
        if (i < ng) {
            int4 q = ((const int4*)guide)[i];
            int c;
            int b = bucket_of(q, &c);
            int lr = atomicAdd(&hist[b], 1);
            packed[k] = (b << 13) | lr;
            ey[k] = (q.y + 1) | ((q.z + 1) << 9) | ((q.w + 1) << 18);
        }
    }
    __syncthreads();
    for (int i = t; i < NB; i += 256) {
        int h = hist[i];
        hist[i] = h ? atomicAdd(&cursor[i], h) : 0;
    }
    __syncthreads();
    #pragma unroll
    for (int k = 0; k < KPT; ++k) {
        if (packed[k] >= 0) {
            int b  = packed[k] >> 13;
            int lr = packed[k] & 8191;
            int i  = base + k * 256 + t;
            int2 e;
            e.x = i | ((b >> 6) << 24);     // class = bucket>>6 (class-major)
            e.y = ey[k];
            sorted[hist[b] + lr] = e;
        }
    }
}

// ---------------- gen_conv helpers (class templated, rank-compacted LDS) ----------------

template<int C>
__device__ __forceinline__ void probe2t(const int* __restrict__ table, int2 s2,
                                        int quad, int* o0, int* o1) {
    int qx = (s2.y & 511) - 1;
    int qy = ((s2.y >> 9) & 511) - 1;
    int qz = ((s2.y >> 18) & 511) - 1;
    int res[2];
    #pragma unroll
    for (int r = 0; r < 2; ++r) {
        int sub = quad + r * 4;
        int offx = (C & 1) ? ((sub & 1) ? 1 : -1) : 0;
        int offy = (C & 2) ? ((sub & 2) ? 1 : -1) : 0;
        int offz = (C & 4) ? ((sub & 4) ? 1 : -1) : 0;
        int px = qx - offx, py = qy - offy, pz = qz - offz;
        bool valid = (s2.x >= 0) & ((sub & ~C & 7) == 0) &
                     ((unsigned)px < 256u) & ((unsigned)py < 256u) & ((unsigned)pz < 256u);
        int lin = (px >> 1) | ((py >> 1) << 7) | ((pz >> 1) << 14);
        int v = table[valid ? lin : 0];
        res[r] = valid ? v : -1;
    }
    *o0 = res[0]; *o1 = res[1];
}

// stage wt[oi] for admissible rank R into LDS slot (R&3), XOR swizzled
template<int C, int R, int NS>
__device__ __forceinline__ void stage_rank(const unsigned short* __restrict__ wt,
                                           unsigned short* bshr, int mm, int jj) {
    if constexpr (R < NS) {
        constexpr int SUB = nth_sub(C, R);
        constexpr int offx = (C & 1) ? ((SUB & 1) ? 1 : -1) : 0;
        constexpr int offy = (C & 2) ? ((SUB & 2) ? 1 : -1) : 0;
        constexpr int offz = (C & 4) ? ((SUB & 4) ? 1 : -1) : 0;
        constexpr int oi = (offx + 1) * 9 + (offy + 1) * 3 + (offz + 1);
        short8 v = *(const short8*)(wt + oi * 2048 + mm * 64 + jj * 8);
        *(short8*)((char*)bshr + (R & 3) * 4096 + mm * 128 + ((jj ^ (mm & 7)) << 4)) = v;
    }
}

template<int USEFB, int C, int R, int NS>
__device__ __forceinline__ void rank_load(const float* __restrict__ feats,
                                          const unsigned short* __restrict__ fb,
                                          int idx0, int idx1,
                                          unsigned long long bal0, unsigned long long bal1,
                                          int m, int quad, short8* A0, short8* A1) {
    if constexpr (R < NS) {
        constexpr int SUB = nth_sub(C, R);
        unsigned long long bal = (SUB < 4) ? bal0 : bal1;
        unsigned rowm = (unsigned)((bal >> ((SUB & 3) * 16)) & 0xffffull);
        short8 z = {0,0,0,0,0,0,0,0};
        A0[R & 3] = z; A1[R & 3] = z;
        if (rowm) {
            int h = __shfl((SUB < 4) ? idx0 : idx1, (SUB & 3) * 16 + m, 64);
            if (h >= 0) {
                if constexpr (USEFB) {
                    const unsigned short* fp = fb + (size_t)h * NIN + quad * 8;
                    A0[R & 3] = *(const short8*)fp;
                    A1[R & 3] = *(const short8*)(fp + 32);
                } else {
                    const float4* fp = (const float4*)(feats + (size_t)h * NIN + quad * 8);
                    float4 fA = fp[0], fB = fp[1];
                    const float4* fp2 = (const float4*)(feats + (size_t)h * NIN + 32 + quad * 8);
                    float4 fC = fp2[0], fD = fp2[1];
                    short8 x, y;
                    x[0] = (short)bf16rne(fA.x); x[1] = (short)bf16rne(fA.y);
                    x[2] = (short)bf16rne(fA.z); x[3] = (short)bf16rne(fA.w);
                    x[4] = (short)bf16rne(fB.x); x[5] = (short)bf16rne(fB.y);
                    x[6] = (short)bf16rne(fB.z); x[7] = (short)bf16rne(fB.w);
                    y[0] = (short)bf16rne(fC.x); y[1] = (short)bf16rne(fC.y);
                    y[2] = (short)bf16rne(fC.z); y[3] = (short)bf16rne(fC.w);
                    y[4] = (short)bf16rne(fD.x); y[5] = (short)bf16rne(fD.y);
                    y[6] = (short)bf16rne(fD.z); y[7] = (short)bf16rne(fD.w);
                    A0[R & 3] = x; A1[R & 3] = y;
                }
            }
        }
    }
}

template<int C, int R, int NS>
__device__ __forceinline__ void rank_mm(const unsigned short* bshr,
                                        unsigned long long bal0, unsigned long long bal1,
                                        int m, int quad, const short8* A0, const short8* A1,
                                        float4v* acc0, float4v* acc1) {
    if constexpr (R < NS) {
        constexpr int SUB = nth_sub(C, R);
        unsigned long long bal = (SUB < 4) ? bal0 : bal1;
        unsigned rowm = (unsigned)((bal >> ((SUB & 3) * 16)) & 0xffffull);
        if (rowm) {
            const char* base = (const char*)bshr + (R & 3) * 4096;
            short8 b00 = *(const short8*)(base + m * 128 + ((quad ^ (m & 7)) << 4));
            short8 b10 = *(const short8*)(base + m * 128 + (((4 + quad) ^ (m & 7)) << 4));
            short8 b01 = *(const short8*)(base + (16 + m) * 128 + ((quad ^ ((16 + m) & 7)) << 4));
            short8 b11 = *(const short8*)(base + (16 + m) * 128 + (((4 + quad) ^ ((16 + m) & 7)) << 4));
            *acc0 = __builtin_amdgcn_mfma_f32_16x16x32_bf16(A0[R & 3], b00, *acc0, 0, 0, 0);
            *acc0 = __builtin_amdgcn_mfma_f32_16x16x32_bf16(A1[R & 3], b10, *acc0, 0, 0, 0);
            *acc1 = __builtin_amdgcn_mfma_f32_16x16x32_bf16(A0[R & 3], b01, *acc1, 0, 0, 0);
            *acc1 = __builtin_amdgcn_mfma_f32_16x16x32_bf16(A1[R & 3], b11, *acc1, 0, 0, 0);
        }
    }
}

template<int USEFB, int C, int P>
__device__ __forceinline__ void phase_tile(const float* __restrict__ feats,
                                           const unsigned short* __restrict__ fb,
                                           const unsigned short* bshr,
                                           int idx0, int idx1,
                                           unsigned long long bal0, unsigned long long bal1,
                                           int m, int quad, float4v* acc0, float4v* acc1) {
    constexpr int NS = 1 << popc8(C);
    short8 A0[4], A1[4];
    rank_load<USEFB, C, P * 4 + 0, NS>(feats, fb, idx0, idx1, bal0, bal1, m, quad, A0, A1);
    rank_load<USEFB, C, P * 4 + 1, NS>(feats, fb, idx0, idx1, bal0, bal1, m, quad, A0, A1);
    rank_load<USEFB, C, P * 4 + 2, NS>(feats, fb, idx0, idx1, bal0, bal1, m, quad, A0, A1);
    rank_load<USEFB, C, P * 4 + 3, NS>(feats, fb, idx0, idx1, bal0, bal1, m, quad, A0, A1);
    rank_mm<C, P * 4 + 0, NS>(bshr, bal0, bal1, m, quad, A0, A1, acc0, acc1);
    rank_mm<C, P * 4 + 1, NS>(bshr, bal0, bal1, m, quad, A0, A1, acc0, acc1);
    rank_mm<C, P * 4 + 2, NS>(bshr, bal0, bal1, m, quad, A0, A1, acc0, acc1);
    rank_mm<C, P * 4 + 3, NS>(bshr, bal0, bal1, m, quad, A0, A1, acc0, acc1);
}

__device__ __forceinline__ void store_tile(int2 s2, unsigned long long eb,
                                           float4v acc0, float4v acc1,
                                           int m, int quad, float bv0, float bv1,
                                           float* __restrict__ out) {
    int id = (s2.x < 0) ? -1 : (s2.x & 0xffffff);
    unsigned e16 = (unsigned)((eb | (eb >> 16) | (eb >> 32) | (eb >> 48)) & 0xffffull);
    #pragma unroll
    for (int r = 0; r < 4; ++r) {
        int mr = quad * 4 + r;
        int idr = __shfl(id, mr, 64);
        if (idr >= 0) {
            bool exr = (e16 >> mr) & 1;
            out[(size_t)idr * NOUT + m]      = exr ? (acc0[r] + bv0) : 0.f;
            out[(size_t)idr * NOUT + 16 + m] = exr ? (acc1[r] + bv1) : 0.f;
        }
    }
}

template<int USEFB, int C>
__device__ __forceinline__ void conv_class(const float* __restrict__ feats,
                                           const unsigned short* __restrict__ fb,
                                           const float* __restrict__ bias,
                                           const int* __restrict__ table,
                                           const int2* __restrict__ sorted,
                                           const unsigned short* __restrict__ wt,
                                           float* __restrict__ out,
                                           int bt0, unsigned short* bshr) {
    constexpr int NS = 1 << popc8(C);
    int tid = threadIdx.x;
    int wid = tid >> 6, lane = tid & 63;
    int m = lane & 15, quad = lane >> 4;
    float bv0 = bias[m], bv1 = bias[16 + m];

    int t0 = bt0 + wid * 2;
    // both tiles' metadata + probes issued upfront (max loads in flight)
    int2 s2a = sorted[t0 * 16 + m];
    int2 s2b = sorted[t0 * 16 + 16 + m];
    int ia0, ia1, ib0, ib1;
    probe2t<C>(table, s2a, quad, &ia0, &ia1);
    probe2t<C>(table, s2b, quad, &ib0, &ib1);

    {   // stage phase 0 (ranks 0..3) into 16 KB LDS
        int mm = tid >> 3, jj = tid & 7;
        stage_rank<C, 0, NS>(wt, bshr, mm, jj);
        stage_rank<C, 1, NS>(wt, bshr, mm, jj);
        stage_rank<C, 2, NS>(wt, bshr, mm, jj);
        stage_rank<C, 3, NS>(wt, bshr, mm, jj);
    }
    __syncthreads();

    unsigned long long balA0 = __ballot(ia0 >= 0), balA1 = __ballot(ia1 >= 0);
    unsigned long long balB0 = __ballot(ib0 >= 0), balB1 = __ballot(ib1 >= 0);

    float4v aA0 = {0.f,0.f,0.f,0.f}, aA1 = {0.f,0.f,0.f,0.f};
    float4v aB0 = {0.f,0.f,0.f,0.f}, aB1 = {0.f,0.f,0.f,0.f};

    phase_tile<USEFB, C, 0>(feats, fb, bshr, ia0, ia1, balA0, balA1, m, quad, &aA0, &aA1);
    phase_tile<USEFB, C, 0>(feats, fb, bshr, ib0, ib1, balB0, balB1, m, quad, &aB0, &aB1);

    if constexpr (NS > 4) {          // class 7 only: restage ranks 4..7
        __syncthreads();
        {
            int mm = tid >> 3, jj = tid & 7;
            stage_rank<C, 4, NS>(wt, bshr, mm, jj);
            stage_rank<C, 5, NS>(wt, bshr, mm, jj);
            stage_rank<C, 6, NS>(wt, bshr, mm, jj);
            stage_rank<C, 7, NS>(wt, bshr, mm, jj);
        }
        __syncthreads();
        phase_tile<USEFB, C, 1>(feats, fb, bshr, ia0, ia1, balA0, balA1, m, quad, &aA0, &aA1);
        phase_tile<USEFB, C, 1>(feats, fb, bshr, ib0, ib1, balB0, balB1, m, quad, &aB0, &aB1);
    }

    store_tile(s2a, balA0 | balA1, aA0, aA1, m, quad, bv0, bv1, out);
    store_tile(s2b, balB0 | balB1, aB0, aB1, m, quad, bv0, bv1, out);
}

template<int USEFB>
__launch_bounds__(256, 6)
__global__ void gen_conv(const float* __restrict__ feats,
                         const unsigned short* __restrict__ fb,
                         const float* __restrict__ bias,
                         const int* __restrict__ table,
                         const int2* __restrict__ sorted,
                         const int* __restrict__ classbase,   // [9], BLKG-aligned
                         const unsigned short* __restrict__ wt,
                         float* __restrict__ out) {
    __shared__ unsigned short bshr[8192];                      // 16 KB

    int nwg = gridDim.x;
    int orig = blockIdx.x;
    int qd = nwg >> 3, rd = nwg & 7;
    int xc = orig & 7, ix = orig >> 3;
    int wg = (xc < rd ? xc * (qd + 1) : rd * (qd + 1) + (xc - rd) * qd) + ix;

    int g0 = wg * BLKG;
    if (g0 >= classbase[8]) return;     // uniform exit
    int c = 0;
    #pragma unroll
    for (int j = 1; j < 8; ++j) c += (g0 >= classbase[j]) ? 1 : 0;
    c = __builtin_amdgcn_readfirstlane(c);
    int bt0 = wg * (BLKG / 16);

    switch (c) {
        case 0: conv_class<USEFB, 0>(feats, fb, bias, table, sorted, wt, out, bt0, bshr); break;
        case 1: conv_class<USEFB, 1>(feats, fb, bias, table, sorted, wt, out, bt0, bshr); break;
        case 2: conv_class<USEFB, 2>(feats, fb, bias, table, sorted, wt, out, bt0, bshr); break;
        case 3: conv_class<USEFB, 3>(feats, fb, bias, table, sorted, wt, out, bt0, bshr); break;
        case 4: conv_class<USEFB, 4>(feats, fb, bias, table, sorted, wt, out, bt0, bshr); break;
        case 5: conv_class<USEFB, 5>(feats, fb, bias, table, sorted, wt, out, bt0, bshr); break;
        case 6: conv_class<USEFB, 6>(feats, fb, bias, table, sorted, wt, out, bt0, bshr); break;
        case 7: conv_class<USEFB, 7>(feats, fb, bias, table, sorted, wt, out, bt0, bshr); break;
    }
}

extern "C" void kernel_launch(void* const* d_in, const int* in_sizes, int n_in,
                              void* d_out, int out_size, void* d_ws, size_t ws_size,
                              hipStream_t stream) {
    const float* feats   = (const float*)d_in[0];
    const float* weights = (const float*)d_in[1];
    const float* bias    = (const float*)d_in[2];
    const int*   coords  = (const int*)d_in[3];
    const int*   guide   = (const int*)d_in[4];
    float* out = (float*)d_out;

    int np = in_sizes[3] / 4;
    int ng = in_sizes[4] / 4;

    int* wsI = (int*)d_ws;
    int SC = (ng + 8 * BLKG + 3) & ~3;       // sorted capacity (entries)
    int A = TSIZE + 2 * SC;                  // sorted is int2
    int* table     = wsI;                    // 2^21
    int2* sorted   = (int2*)(wsI + TSIZE);   // SC entries, -1 padded
    int* count     = wsI + A;                // 512
    int* cursor    = wsI + A + 512;          // 512
    int* classbase = wsI + A + 1024;         // 9 (+pad to 16)
    unsigned short* wt = (unsigned short*)(wsI + A + 1040);   // 27*32*64 bf16
    unsigned short* fb = (unsigned short*)(wsI + A + 1040 + 27648);
    size_t need = ((size_t)A + 1040 + 27648) * 4 + (size_t)np * NIN * 2;
    int usefb = (ws_size >= need) ? 1 : 0;

    hipMemsetAsync(count, 0, NB * sizeof(int), stream);

    int n4 = A / 4;
    int fn4 = usefb ? np * (NIN / 4) : 0;
    int prep_n = n4 > fn4 ? n4 : fn4;
    if (prep_n < 27 * 64 * 32) prep_n = 27 * 64 * 32;
    int prep_blocks = (prep_n + 255) / 256;
    int cblocks = (ng + CHUNK - 1) / CHUNK;
    if (prep_blocks < cblocks) prep_blocks = cblocks;
    hipLaunchKernelGGL(prep, dim3(prep_blocks), dim3(256), 0, stream,
                       (int4*)wsI, n4, weights, wt, feats, fb, fn4, guide, ng, count);

    hipLaunchKernelGGL(scanB, dim3(1), dim3(512), 0, stream, count, cursor, classbase);

    int sb1 = (np + 255) / 256;
    int sblocks = sb1 > cblocks ? sb1 : cblocks;
    hipLaunchKernelGGL(scat, dim3(sblocks), dim3(256), 0, stream,
                       coords, np, table, guide, ng, cursor, sorted);

    int maxguides = ng + 8 * (BLKG - 1);
    int blocks = (maxguides + BLKG - 1) / BLKG;
    if (usefb) {
        hipLaunchKernelGGL((gen_conv<1>), dim3(blocks), dim3(256), 0, stream,
                           feats, fb, bias, table, sorted, classbase, wt, out);
    } else {
        hipLaunchKernelGGL((gen_conv<0>), dim3(blocks), dim3(256), 0, stream,
                           feats, fb, bias, table, sorted, classbase, wt, out);
    }
}